// Round 1
// baseline (23.714 us; speedup 1.0000x reference)
//
#include <hip/hip_runtime.h>

// Problem constants (from reference): x [B=4, L=4096, D=256] fp32, q [256] fp32.
// Math reduction: scores are constant along the softmax axis -> softmax is
// uniform over the causal prefix -> out[b,i,:] = mean(x[b,0..i,:]).
// => causal cumulative mean; q is mathematically irrelevant.

#define BB 4
#define LL 4096
#define DD 256
#define NCHUNK 256
#define CHUNK 16          // LL / NCHUNK
#define COLS 1024         // BB * DD
#define COLS4 256         // COLS / 4

// Phase 1: per-chunk column sums. Grid: NCHUNK blocks x 256 threads.
// Thread t owns float4 column-group: b = t/64, d4 = t%64 (cols 4*d4..4*d4+3).
// Wave lanes span consecutive d4 -> fully coalesced 1 KiB/wave float4 loads.
__global__ __launch_bounds__(256) void cap_partial_sums(
    const float* __restrict__ x, float* __restrict__ P) {
    const int t  = threadIdx.x;
    const int c  = blockIdx.x;
    const int b  = t >> 6;
    const int d4 = t & 63;
    const float4* xb = reinterpret_cast<const float4*>(x + (size_t)b * LL * DD) + d4;
    const int l0 = c * CHUNK;
    float4 s = {0.f, 0.f, 0.f, 0.f};
#pragma unroll
    for (int k = 0; k < CHUNK; ++k) {
        float4 v = xb[(size_t)(l0 + k) * (DD / 4)];
        s.x += v.x; s.y += v.y; s.z += v.z; s.w += v.w;
    }
    // Layout P[c][col] (c-major): coalesced float4 store.
    reinterpret_cast<float4*>(P)[c * COLS4 + t] = s;
}

// Phase 2: in-place exclusive scan of the NCHUNK partials per column.
// Grid: 16 blocks x 64 threads; thread -> one scalar column.
// Loads tiled 32-deep and unrolled so 32 independent loads are in flight.
__global__ __launch_bounds__(64) void cap_scan_partials(float* __restrict__ P) {
    const int col = blockIdx.x * 64 + threadIdx.x;   // 0..1023
    float run = 0.f;
#pragma unroll 1
    for (int tile = 0; tile < NCHUNK / 32; ++tile) {
        float v[32];
#pragma unroll
        for (int j = 0; j < 32; ++j) v[j] = P[(size_t)(tile * 32 + j) * COLS + col];
#pragma unroll
        for (int j = 0; j < 32; ++j) { float tmp = v[j]; v[j] = run; run += tmp; }
#pragma unroll
        for (int j = 0; j < 32; ++j) P[(size_t)(tile * 32 + j) * COLS + col] = v[j];
    }
}

// Phase 3: running prefix within chunk + exclusive base, write mean.
// Same geometry as phase 1; x re-read likely L2/L3-resident.
__global__ __launch_bounds__(256) void cap_final_pass(
    const float* __restrict__ x, const float* __restrict__ P,
    float* __restrict__ out) {
    const int t  = threadIdx.x;
    const int c  = blockIdx.x;
    const int b  = t >> 6;
    const int d4 = t & 63;
    const float4* xb = reinterpret_cast<const float4*>(x + (size_t)b * LL * DD) + d4;
    float4*       ob = reinterpret_cast<float4*>(out + (size_t)b * LL * DD) + d4;
    float4 run = reinterpret_cast<const float4*>(P)[c * COLS4 + t];
    const int l0 = c * CHUNK;
#pragma unroll
    for (int k = 0; k < CHUNK; ++k) {
        const int l = l0 + k;
        float4 v = xb[(size_t)l * (DD / 4)];
        run.x += v.x; run.y += v.y; run.z += v.z; run.w += v.w;
        const float inv = 1.0f / (float)(l + 1);
        float4 o = { run.x * inv, run.y * inv, run.z * inv, run.w * inv };
        ob[(size_t)l * (DD / 4)] = o;
    }
}

extern "C" void kernel_launch(void* const* d_in, const int* in_sizes, int n_in,
                              void* d_out, int out_size, void* d_ws, size_t ws_size,
                              hipStream_t stream) {
    const float* x = (const float*)d_in[0];
    // d_in[1] (q) is mathematically irrelevant: softmax over a constant row is
    // uniform on the causal prefix.
    float* out = (float*)d_out;
    float* P   = (float*)d_ws;   // NCHUNK * COLS * 4 B = 1 MiB of scratch

    cap_partial_sums<<<dim3(NCHUNK), dim3(256), 0, stream>>>(x, P);
    cap_scan_partials<<<dim3(16), dim3(64), 0, stream>>>(P);
    cap_final_pass<<<dim3(NCHUNK), dim3(256), 0, stream>>>(x, P, out);
}